// Round 24
// baseline (122.870 us; speedup 1.0000x reference)
//
#include <hip/hip_runtime.h>
#include <hip/hip_bf16.h>

#define N_NODES 100000
#define N_EDGES 1600000
#define IN_DIM  256
#define OUT_DIM 128

#define GEMM_ROWS   32
#define GEMM_BLOCKS (N_NODES / GEMM_ROWS)          // 3125 exact

#define NBUCK   391                                // ceil(100000 / 256)
#define BSHIFT  8                                  // 256 nodes per bucket
#define BCAP    5120                               // per-bucket capacity (mean 4096)
#define BSTRIDE 16                                 // bcur padding: 1 line per bucket
#define EPB     2048                               // edges per coarse block
#define BIN_BLOCKS ((N_EDGES + EPB - 1) / EPB)     // 782
#define TOTAL_BLOCKS (GEMM_BLOCKS + BIN_BLOCKS)    // 3907

typedef __attribute__((ext_vector_type(8))) short bf16x8;
typedef __attribute__((ext_vector_type(4))) float f32x4;

__device__ __forceinline__ ushort f2bf(float f) {
    union { float f; unsigned u; } v; v.f = f;
    unsigned r = v.u + 0x7FFF + ((v.u >> 16) & 1);   // RNE
    return (ushort)(r >> 16);
}
__device__ __forceinline__ float bflo(unsigned u) {
    union { unsigned u; float f; } v; v.u = u << 16; return v.f;
}
__device__ __forceinline__ float bfhi(unsigned u) {
    union { unsigned u; float f; } v; v.u = u & 0xFFFF0000u; return v.f;
}

// ------- Pack W[256,128] f32 -> bf16 fragment-major (+ zero bcur) ----------
__global__ __launch_bounds__(256) void pack_w(const float* __restrict__ W,
                                              ushort* __restrict__ Wp,
                                              int* __restrict__ bcur) {
    const int t = blockIdx.x * 256 + threadIdx.x;
    if (blockIdx.x == 0) {                         // fold: zero bucket cursors
        for (int i = threadIdx.x; i < NBUCK * BSTRIDE; i += 256) bcur[i] = 0;
    }
    if (t >= 4096) return;
    const int kk = t >> 9, n = (t >> 6) & 7, l = t & 63;
    const int kbase = kk * 32 + (l >> 4) * 8;
    const int col   = n * 16 + (l & 15);
    ushort* o = Wp + (size_t)t * 8;
#pragma unroll
    for (int j = 0; j < 8; ++j)
        o[j] = f2bf(W[(size_t)(kbase + j) * OUT_DIM + col]);
}

// --- Fused (4:1 INTERLEAVED): 32-row MFMA GEMM (B-frags preloaded to regs) -
// --- + EPB-2048 sorted coarse binning into 391 buckets. ---------------------
__global__ __launch_bounds__(256, 5) void gemm_coarse(const float* __restrict__ X,
                                                      const bf16x8* __restrict__ Bp,
                                                      ushort* __restrict__ H,
                                                      const int* __restrict__ esrc,
                                                      const int* __restrict__ edst,
                                                      const float* __restrict__ eval,
                                                      int* __restrict__ bcur,
                                                      int2* __restrict__ binned) {
    __shared__ char smem[28672];                   // GEMM 16.4KB / coarse 28KB

    const int tid  = threadIdx.x;
    const int lane = tid & 63;
    const int wv   = tid >> 6;
    const int bid  = blockIdx.x;

    const bool is_coarse = ((bid % 5) == 4) || (bid == TOTAL_BLOCKS - 1);

    if (is_coarse) {
        // ---- coarse binning with in-LDS counting sort (2048-edge chunk) ----
        const int blk = (bid == TOTAL_BLOCKS - 1) ? (BIN_BLOCKS - 1) : (bid / 5);
        int*    cnt   = (int*)smem;                // [392]
        int*    lbase = (int*)smem + 512;          // [392]
        int*    sbase = (int*)smem + 1024;         // [392]
        int*    cur   = (int*)smem + 1536;         // [392]
        int2*   lrec  = (int2*)(smem + 8192);      // [2048] 16 KB
        ushort* lbid  = (ushort*)(smem + 24576);   // [2048] 4 KB

        const int cb  = blk * EPB;
        const int lim = (N_EDGES - cb < EPB) ? (N_EDGES - cb) : EPB;

        cnt[tid] = 0;
        if (tid < 136) cnt[256 + tid] = 0;         // 392 entries
        __syncthreads();
        for (int i = tid; i < lim; i += 256)
            atomicAdd(&cnt[edst[cb + i] >> BSHIFT], 1);
        __syncthreads();

        // exclusive pair-scan of cnt[0..391]: threads 0..195 own (2t, 2t+1)
        {
            __shared__ int wsum[4];
            int a0 = 0, a1 = 0, ts = 0, sv = 0;
            if (tid < 196) {
                a0 = cnt[2 * tid];
                a1 = cnt[2 * tid + 1];
                ts = a0 + a1;
                sv = ts;
#pragma unroll
                for (int d = 1; d < 64; d <<= 1) {
                    const int t = __shfl_up(sv, d, 64);
                    if (lane >= d) sv += t;
                }
                if (lane == 63 || tid == 195) wsum[wv] = sv;
            }
            __syncthreads();
            if (tid < 196) {
                int wx = 0;
#pragma unroll
                for (int w = 0; w < 4; ++w) if (w < wv) wx += wsum[w];
                const int ex = wx + sv - ts;       // exclusive prefix of pair
                lbase[2 * tid]     = ex;
                lbase[2 * tid + 1] = ex + a0;
                cur[2 * tid]       = ex;
                cur[2 * tid + 1]   = ex + a0;
                sbase[2 * tid]     = a0 ? atomicAdd(&bcur[(2 * tid) * BSTRIDE], a0) : 0;
                sbase[2 * tid + 1] = a1 ? atomicAdd(&bcur[(2 * tid + 1) * BSTRIDE], a1) : 0;
            }
        }
        __syncthreads();

        // scatter into LDS in bucket-sorted order
        for (int i = tid; i < lim; i += 256) {
            const int d = edst[cb + i];
            const int b = d >> BSHIFT;
            const int pos = atomicAdd(&cur[b], 1);
            int2 rec;
            rec.x = esrc[cb + i] | ((d & 255) << 20);
            rec.y = __float_as_int(eval[cb + i]);
            lrec[pos] = rec;
            lbid[pos] = (ushort)b;
        }
        __syncthreads();

        // write out sorted: consecutive i -> consecutive global positions
        for (int i = tid; i < lim; i += 256) {
            const int b   = lbid[i];
            const int off = sbase[b] + (i - lbase[b]);
            if (off < BCAP)
                binned[(size_t)b * BCAP + off] = lrec[i];
        }
        return;
    }

    // ---- GEMM: 32 rows x 128 cols; 4 waves each own 32 rows x 32 cols ----
    const int gidx = bid - bid / 5;                // de-interleaved GEMM index
    ushort* xt = (ushort*)smem;
    const int row0 = gidx * GEMM_ROWS;             // exact: no bounds checks
    const int wid  = wv;                           // col quarter 0..3

    // stage: 8 iters, 4 rows/iter, convert f32->bf16, swizzled LDS store
#pragma unroll 4
    for (int it = 0; it < 8; ++it) {
        const int tr = it * 4 + (tid >> 6);
        const int tc = (tid & 63) * 4;
        const float4 v = *reinterpret_cast<const float4*>(
            X + (size_t)(row0 + tr) * IN_DIM + tc);
        ushort4 b4;
        b4.x = f2bf(v.x); b4.y = f2bf(v.y); b4.z = f2bf(v.z); b4.w = f2bf(v.w);
        const int byte = (tr * 512 + tc * 2) ^ ((tr & 7) << 4);
        *reinterpret_cast<ushort4*>((char*)xt + byte) = b4;
    }

    // preload ALL B fragments for this wave (16 x 16B = 64 VGPRs, L2-hot);
    bf16x8 Bfr[8][2];
#pragma unroll
    for (int kk = 0; kk < 8; ++kk)
#pragma unroll
        for (int n = 0; n < 2; ++n)
            Bfr[kk][n] = Bp[(size_t)(kk * 8 + wid * 2 + n) * 64 + lane];

    __syncthreads();

    const int rlo  = lane & 15;
    const int kseg = lane >> 4;
    const int rl0  = rlo;                          // A-frag local rows
    const int rl1  = rlo + 16;
    const int rxor = (rlo & 7) << 4;

    f32x4 acc[2][2] = {};

#pragma unroll
    for (int kk = 0; kk < 8; ++kk) {
        const int cb2 = (kk * 64 + kseg * 16) ^ rxor;
        const bf16x8 A0 = *reinterpret_cast<const bf16x8*>((const char*)xt + rl0 * 512 + cb2);
        const bf16x8 A1 = *reinterpret_cast<const bf16x8*>((const char*)xt + rl1 * 512 + cb2);
#pragma unroll
        for (int n = 0; n < 2; ++n) {
            acc[0][n] = __builtin_amdgcn_mfma_f32_16x16x32_bf16(A0, Bfr[kk][n], acc[0][n], 0, 0, 0);
            acc[1][n] = __builtin_amdgcn_mfma_f32_16x16x32_bf16(A1, Bfr[kk][n], acc[1][n], 0, 0, 0);
        }
    }

    // C/D layout: col = wid*32 + n*16 + rlo, row = i*16 + kseg*4 + r
#pragma unroll
    for (int i = 0; i < 2; ++i)
#pragma unroll
        for (int r = 0; r < 4; ++r)
#pragma unroll
            for (int n = 0; n < 2; ++n)
                H[(size_t)(row0 + i * 16 + kseg * 4 + r) * OUT_DIM
                  + wid * 32 + n * 16 + rlo] = f2bf(acc[i][n][r]);
}

// --- Fused fine+pull, records sorted into LDS (no global recs array) -------
// Block b: hist binned[b] -> local scan -> scatter -> LDS sorted records ->
// pull 256 nodes from LDS. ~43 KB LDS -> 2 blocks/CU (thread cap).
__global__ __launch_bounds__(1024) void bin_pull(const int* __restrict__ bcur,
                                                 const int2* __restrict__ binned,
                                                 const ushort* __restrict__ H,
                                                 float* __restrict__ out) {
    __shared__ int2 srec[BCAP];                    // 40 KB sorted records
    __shared__ int nh[256];
    __shared__ int cur[256];
    __shared__ int ws[4];
    const int b   = blockIdx.x;
    const int tid = threadIdx.x, lane = tid & 63, wid = tid >> 6;
    const int node0 = b << BSHIFT;
    int nn = N_NODES - node0; if (nn > 256) nn = 256;
    int size = bcur[b * BSTRIDE]; if (size > BCAP) size = BCAP;
    const int2* in = binned + (size_t)b * BCAP;

    if (tid < 256) nh[tid] = 0;
    __syncthreads();
    for (int k = tid; k < size; k += 1024)
        atomicAdd(&nh[(in[k].x >> 20) & 255], 1);
    __syncthreads();

    // exclusive scan over nh[0..255]: thread t owns entry t (4 waves)
    int v = 0, sv = 0;
    if (tid < 256) {
        v = nh[tid];
        sv = v;
#pragma unroll
        for (int d = 1; d < 64; d <<= 1) {
            const int t = __shfl_up(sv, d, 64);
            if (lane >= d) sv += t;
        }
        if (lane == 63) ws[wid] = sv;
    }
    __syncthreads();
    if (tid < 256) {
        int wx = 0;
#pragma unroll
        for (int w = 0; w < 4; ++w) if (w < wid) wx += ws[w];
        cur[tid] = wx + sv - v;                    // exclusive prefix
    }
    __syncthreads();

    // scatter: global binned (L2-hot) -> LDS sorted by node
    for (int k = tid; k < size; k += 1024) {
        const int2 r = in[k];
        const int pos = atomicAdd(&cur[(r.x >> 20) & 255], 1);
        int2 o; o.x = r.x & 0xFFFFF; o.y = r.y;
        srec[pos] = o;
    }
    __syncthreads();                               // bucket fully sorted in LDS

    // ---- pull: 64 groups x 16 lanes; group handles 4 consecutive nodes ----
    const int grp = tid >> 4;                      // 0..63
    const int c   = tid & 15;                      // 16B col-chunk

#define ACC(h, v)  {                                                      \
        p0 = fmaf(v, bflo(h.x), p0);  p1 = fmaf(v, bfhi(h.x), p1);        \
        p2 = fmaf(v, bflo(h.y), p2);  p3 = fmaf(v, bfhi(h.y), p3);        \
        p4 = fmaf(v, bflo(h.z), p4);  p5 = fmaf(v, bfhi(h.z), p5);        \
        p6 = fmaf(v, bflo(h.w), p6);  p7 = fmaf(v, bfhi(h.w), p7); }

    for (int j = 0; j < 4; ++j) {
        const int ln = grp * 4 + j;                // local node 0..255
        if (ln >= nn) break;
        const int end = cur[ln];
        const int beg = end - nh[ln];

        float p0 = 0.f, p1 = 0.f, p2 = 0.f, p3 = 0.f;
        float p4 = 0.f, p5 = 0.f, p6 = 0.f, p7 = 0.f;

        int e = beg;
        for (; e + 7 < end; e += 8) {
            const int2 r0 = srec[e + 0], r1 = srec[e + 1];
            const int2 r2 = srec[e + 2], r3 = srec[e + 3];
            const int2 r4 = srec[e + 4], r5 = srec[e + 5];
            const int2 r6 = srec[e + 6], r7 = srec[e + 7];
            const uint4 h0 = *((const uint4*)(H + (size_t)r0.x * OUT_DIM) + c);
            const uint4 h1 = *((const uint4*)(H + (size_t)r1.x * OUT_DIM) + c);
            const uint4 h2 = *((const uint4*)(H + (size_t)r2.x * OUT_DIM) + c);
            const uint4 h3 = *((const uint4*)(H + (size_t)r3.x * OUT_DIM) + c);
            const uint4 h4 = *((const uint4*)(H + (size_t)r4.x * OUT_DIM) + c);
            const uint4 h5 = *((const uint4*)(H + (size_t)r5.x * OUT_DIM) + c);
            const uint4 h6 = *((const uint4*)(H + (size_t)r6.x * OUT_DIM) + c);
            const uint4 h7 = *((const uint4*)(H + (size_t)r7.x * OUT_DIM) + c);
            ACC(h0, __int_as_float(r0.y));  ACC(h1, __int_as_float(r1.y));
            ACC(h2, __int_as_float(r2.y));  ACC(h3, __int_as_float(r3.y));
            ACC(h4, __int_as_float(r4.y));  ACC(h5, __int_as_float(r5.y));
            ACC(h6, __int_as_float(r6.y));  ACC(h7, __int_as_float(r7.y));
        }
        for (; e + 1 < end; e += 2) {
            const int2 r0 = srec[e + 0], r1 = srec[e + 1];
            const uint4 h0 = *((const uint4*)(H + (size_t)r0.x * OUT_DIM) + c);
            const uint4 h1 = *((const uint4*)(H + (size_t)r1.x * OUT_DIM) + c);
            ACC(h0, __int_as_float(r0.y));  ACC(h1, __int_as_float(r1.y));
        }
        if (e < end) {
            const int2 r0 = srec[e];
            const uint4 h0 = *((const uint4*)(H + (size_t)r0.x * OUT_DIM) + c);
            ACC(h0, __int_as_float(r0.y));
        }

        float* op = out + (size_t)(node0 + ln) * OUT_DIM + c * 8;
        float4 o0, o1;
        o0.x = fmaxf(p0, 0.f); o0.y = fmaxf(p1, 0.f);
        o0.z = fmaxf(p2, 0.f); o0.w = fmaxf(p3, 0.f);
        o1.x = fmaxf(p4, 0.f); o1.y = fmaxf(p5, 0.f);
        o1.z = fmaxf(p6, 0.f); o1.w = fmaxf(p7, 0.f);
        *reinterpret_cast<float4*>(op)     = o0;
        *reinterpret_cast<float4*>(op + 4) = o1;
    }
#undef ACC
}

extern "C" void kernel_launch(void* const* d_in, const int* in_sizes, int n_in,
                              void* d_out, int out_size, void* d_ws, size_t ws_size,
                              hipStream_t stream) {
    const float* X    = (const float*)d_in[0];   // [N_NODES, IN_DIM]
    const float* W    = (const float*)d_in[1];   // [IN_DIM, OUT_DIM]
    const int*   esrc = (const int*)d_in[2];     // [N_EDGES]
    const int*   edst = (const int*)d_in[3];     // [N_EDGES]
    const float* eval = (const float*)d_in[4];   // [N_EDGES]
    float*       out  = (float*)d_out;           // [N_NODES, OUT_DIM]

    // Workspace layout (~42 MB)
    char* ws = (char*)d_ws;
    ushort* Hb     = (ushort*)ws;  ws += (size_t)N_NODES * OUT_DIM * sizeof(ushort);   // 25.6 MB
    ushort* Wp     = (ushort*)ws;  ws += (size_t)4096 * 8 * sizeof(ushort);            // 64 KB
    int*    bcur   = (int*)ws;     ws += (size_t)NBUCK * BSTRIDE * 4;                  // 25 KB padded
    int2*   binned = (int2*)ws;    // 16.0 MB

    // 1) Pack W (+ zero bucket cursors); interleaved [GEMM || sorted coarse]
    pack_w<<<16, 256, 0, stream>>>(W, Wp, bcur);
    gemm_coarse<<<TOTAL_BLOCKS, 256, 0, stream>>>(X, (const bf16x8*)Wp, Hb,
                                                  esrc, edst, eval, bcur, binned);

    // 2) Fused per-bucket CSR-in-LDS + pull-SpMM + ReLU
    bin_pull<<<NBUCK, 1024, 0, stream>>>(bcur, binned, Hb, out);
}

// Round 25
// 113.218 us; speedup vs baseline: 1.0853x; 1.0853x over previous
//
#include <hip/hip_runtime.h>
#include <hip/hip_bf16.h>

#define N_NODES 100000
#define N_EDGES 1600000
#define IN_DIM  256
#define OUT_DIM 128

#define GEMM_ROWS   32
#define GEMM_BLOCKS (N_NODES / GEMM_ROWS)          // 3125 exact

#define NBUCK   196                                // ceil(100000 / 512)
#define BSHIFT  9                                  // 512 nodes per bucket
#define BCAP    10240                              // per-bucket capacity (mean 8192)
#define BCAP_H  5120                               // per-half capacity (mean 4096)
#define BSTRIDE 16                                 // bcur padding: 1 line per bucket
#define EPB     2048                               // edges per coarse block
#define BIN_BLOCKS ((N_EDGES + EPB - 1) / EPB)     // 782
#define TOTAL_BLOCKS (GEMM_BLOCKS + BIN_BLOCKS)    // 3907

typedef __attribute__((ext_vector_type(8))) short bf16x8;
typedef __attribute__((ext_vector_type(4))) float f32x4;

__device__ __forceinline__ ushort f2bf(float f) {
    union { float f; unsigned u; } v; v.f = f;
    unsigned r = v.u + 0x7FFF + ((v.u >> 16) & 1);   // RNE
    return (ushort)(r >> 16);
}
__device__ __forceinline__ float bflo(unsigned u) {
    union { unsigned u; float f; } v; v.u = u << 16; return v.f;
}
__device__ __forceinline__ float bfhi(unsigned u) {
    union { unsigned u; float f; } v; v.u = u & 0xFFFF0000u; return v.f;
}

// ------- Pack W[256,128] f32 -> bf16 fragment-major (+ zero bcur) ----------
__global__ __launch_bounds__(256) void pack_w(const float* __restrict__ W,
                                              ushort* __restrict__ Wp,
                                              int* __restrict__ bcur) {
    const int t = blockIdx.x * 256 + threadIdx.x;
    if (blockIdx.x == 0) {                         // fold: zero bucket cursors
        for (int i = threadIdx.x; i < NBUCK * BSTRIDE; i += 256) bcur[i] = 0;
    }
    if (t >= 4096) return;
    const int kk = t >> 9, n = (t >> 6) & 7, l = t & 63;
    const int kbase = kk * 32 + (l >> 4) * 8;
    const int col   = n * 16 + (l & 15);
    ushort* o = Wp + (size_t)t * 8;
#pragma unroll
    for (int j = 0; j < 8; ++j)
        o[j] = f2bf(W[(size_t)(kbase + j) * OUT_DIM + col]);
}

// --- Fused (4:1 INTERLEAVED): 32-row MFMA GEMM (B-frags preloaded to regs) -
// --- + EPB-2048 sorted coarse binning. launch_bounds(256,5): 102 VGPRs. ----
__global__ __launch_bounds__(256, 5) void gemm_coarse(const float* __restrict__ X,
                                                      const bf16x8* __restrict__ Bp,
                                                      ushort* __restrict__ H,
                                                      const int* __restrict__ esrc,
                                                      const int* __restrict__ edst,
                                                      const float* __restrict__ eval,
                                                      int* __restrict__ bcur,
                                                      int2* __restrict__ binned) {
    __shared__ char smem[22656];                   // GEMM 16.1KB / coarse 22.1KB

    const int tid  = threadIdx.x;
    const int lane = tid & 63;
    const int wv   = tid >> 6;
    const int bid  = blockIdx.x;

    const bool is_coarse = ((bid % 5) == 4) || (bid == TOTAL_BLOCKS - 1);

    if (is_coarse) {
        // ---- coarse binning with in-LDS counting sort (2048-edge chunk) ----
        const int blk = (bid == TOTAL_BLOCKS - 1) ? (BIN_BLOCKS - 1) : (bid / 5);
        int*   cnt   = (int*)smem;                 // [196]
        int*   lbase = (int*)smem + 256;           // [196]
        int*   sbase = (int*)smem + 512;           // [196]
        int*   cur   = (int*)smem + 768;           // [196]
        int2*  lrec  = (int2*)(smem + 4096);       // [2048] 16 KB
        unsigned char* lbid = (unsigned char*)smem + 20480;  // [2048]

        const int cb  = blk * EPB;
        const int lim = (N_EDGES - cb < EPB) ? (N_EDGES - cb) : EPB;

        if (tid < NBUCK) cnt[tid] = 0;
        __syncthreads();
        for (int i = tid; i < lim; i += 256)
            atomicAdd(&cnt[edst[cb + i] >> BSHIFT], 1);
        __syncthreads();

        // exclusive scan of cnt[0..195] -> lbase
        {
            __shared__ int wsum[4];
            const int v = (tid < NBUCK) ? cnt[tid] : 0;
            int sv = v;
#pragma unroll
            for (int d = 1; d < 64; d <<= 1) {
                const int t = __shfl_up(sv, d, 64);
                if (lane >= d) sv += t;
            }
            if (lane == 63) wsum[wv] = sv;
            __syncthreads();
            int wx = 0;
#pragma unroll
            for (int w = 0; w < 4; ++w) if (w < wv) wx += wsum[w];
            if (tid < NBUCK) {
                const int ex = wx + sv - v;
                lbase[tid] = ex;
                cur[tid]   = ex;
                sbase[tid] = v ? atomicAdd(&bcur[tid * BSTRIDE], v) : 0;
            }
        }
        __syncthreads();

        // scatter into LDS in bucket-sorted order
        for (int i = tid; i < lim; i += 256) {
            const int d = edst[cb + i];
            const int b = d >> BSHIFT;
            const int pos = atomicAdd(&cur[b], 1);
            int2 rec;
            rec.x = esrc[cb + i] | ((d & 511) << 20);
            rec.y = __float_as_int(eval[cb + i]);
            lrec[pos] = rec;
            lbid[pos] = (unsigned char)b;
        }
        __syncthreads();

        // write out sorted: consecutive i -> consecutive global positions
        for (int i = tid; i < lim; i += 256) {
            const int b   = lbid[i];
            const int off = sbase[b] + (i - lbase[b]);
            if (off < BCAP)
                binned[(size_t)b * BCAP + off] = lrec[i];
        }
        return;
    }

    // ---- GEMM: 32 rows x 128 cols; 4 waves each own 32 rows x 32 cols ----
    const int gidx = bid - bid / 5;                // de-interleaved GEMM index
    ushort* xt = (ushort*)smem;
    const int row0 = gidx * GEMM_ROWS;             // exact: no bounds checks
    const int wid  = wv;                           // col quarter 0..3

    // stage: 8 iters, 4 rows/iter, convert f32->bf16, swizzled LDS store
#pragma unroll 4
    for (int it = 0; it < 8; ++it) {
        const int tr = it * 4 + (tid >> 6);
        const int tc = (tid & 63) * 4;
        const float4 v = *reinterpret_cast<const float4*>(
            X + (size_t)(row0 + tr) * IN_DIM + tc);
        ushort4 b4;
        b4.x = f2bf(v.x); b4.y = f2bf(v.y); b4.z = f2bf(v.z); b4.w = f2bf(v.w);
        const int byte = (tr * 512 + tc * 2) ^ ((tr & 7) << 4);
        *reinterpret_cast<ushort4*>((char*)xt + byte) = b4;
    }

    // preload ALL B fragments for this wave (16 x 16B = 64 VGPRs, L2-hot);
    bf16x8 Bfr[8][2];
#pragma unroll
    for (int kk = 0; kk < 8; ++kk)
#pragma unroll
        for (int n = 0; n < 2; ++n)
            Bfr[kk][n] = Bp[(size_t)(kk * 8 + wid * 2 + n) * 64 + lane];

    __syncthreads();

    const int rlo  = lane & 15;
    const int kseg = lane >> 4;
    const int rl0  = rlo;                          // A-frag local rows
    const int rl1  = rlo + 16;
    const int rxor = (rlo & 7) << 4;

    f32x4 acc[2][2] = {};

#pragma unroll
    for (int kk = 0; kk < 8; ++kk) {
        const int cb2 = (kk * 64 + kseg * 16) ^ rxor;
        const bf16x8 A0 = *reinterpret_cast<const bf16x8*>((const char*)xt + rl0 * 512 + cb2);
        const bf16x8 A1 = *reinterpret_cast<const bf16x8*>((const char*)xt + rl1 * 512 + cb2);
#pragma unroll
        for (int n = 0; n < 2; ++n) {
            acc[0][n] = __builtin_amdgcn_mfma_f32_16x16x32_bf16(A0, Bfr[kk][n], acc[0][n], 0, 0, 0);
            acc[1][n] = __builtin_amdgcn_mfma_f32_16x16x32_bf16(A1, Bfr[kk][n], acc[1][n], 0, 0, 0);
        }
    }

    // C/D layout: col = wid*32 + n*16 + rlo, row = i*16 + kseg*4 + r
#pragma unroll
    for (int i = 0; i < 2; ++i)
#pragma unroll
        for (int r = 0; r < 4; ++r)
#pragma unroll
            for (int n = 0; n < 2; ++n)
                H[(size_t)(row0 + i * 16 + kseg * 4 + r) * OUT_DIM
                  + wid * 32 + n * 16 + rlo] = f2bf(acc[i][n][r]);
}

// --- Fused fine+pull on HALF-buckets: grid = 2*NBUCK (392 blocks) ----------
// Block handles 256 nodes (half of bucket b): filters bucket b's binned
// records by half-bit, sorts them into LDS, pulls from LDS. ~43 KB LDS ->
// 2 blocks/CU; 392 blocks cover all 256 CUs.
__global__ __launch_bounds__(1024) void bin_pull(const int* __restrict__ bcur,
                                                 const int2* __restrict__ binned,
                                                 const ushort* __restrict__ H,
                                                 float* __restrict__ out) {
    __shared__ int2 srec[BCAP_H];                  // 40 KB sorted records
    __shared__ int nh[256];
    __shared__ int cur[256];
    __shared__ int ws[4];
    const int b    = blockIdx.x >> 1;
    const int half = blockIdx.x & 1;
    const int tid = threadIdx.x, lane = tid & 63, wid = tid >> 6;
    const int node0 = (b << BSHIFT) + half * 256;
    int nn = N_NODES - node0; if (nn > 256) nn = 256;
    if (nn <= 0) return;                           // uniform across block
    int size = bcur[b * BSTRIDE]; if (size > BCAP) size = BCAP;
    const int2* in = binned + (size_t)b * BCAP;

    if (tid < 256) nh[tid] = 0;
    __syncthreads();
    for (int k = tid; k < size; k += 1024) {
        const int ln9 = (in[k].x >> 20) & 511;
        if ((ln9 >> 8) == half) atomicAdd(&nh[ln9 & 255], 1);
    }
    __syncthreads();

    // exclusive scan over nh[0..255]: thread t owns entry t (4 waves)
    int v = 0, sv = 0;
    if (tid < 256) {
        v = nh[tid];
        sv = v;
#pragma unroll
        for (int d = 1; d < 64; d <<= 1) {
            const int t = __shfl_up(sv, d, 64);
            if (lane >= d) sv += t;
        }
        if (lane == 63) ws[wid] = sv;
    }
    __syncthreads();
    if (tid < 256) {
        int wx = 0;
#pragma unroll
        for (int w = 0; w < 4; ++w) if (w < wid) wx += ws[w];
        cur[tid] = wx + sv - v;                    // exclusive prefix
    }
    __syncthreads();

    // scatter: global binned (L2-hot) -> LDS sorted by node (this half only)
    for (int k = tid; k < size; k += 1024) {
        const int2 r = in[k];
        const int ln9 = (r.x >> 20) & 511;
        if ((ln9 >> 8) != half) continue;
        const int pos = atomicAdd(&cur[ln9 & 255], 1);
        if (pos < BCAP_H) {
            int2 o; o.x = r.x & 0xFFFFF; o.y = r.y;
            srec[pos] = o;
        }
    }
    __syncthreads();                               // half-bucket sorted in LDS

    // ---- pull: 64 groups x 16 lanes; group handles 4 consecutive nodes ----
    const int grp = tid >> 4;                      // 0..63
    const int c   = tid & 15;                      // 16B col-chunk

#define ACC(h, v)  {                                                      \
        p0 = fmaf(v, bflo(h.x), p0);  p1 = fmaf(v, bfhi(h.x), p1);        \
        p2 = fmaf(v, bflo(h.y), p2);  p3 = fmaf(v, bfhi(h.y), p3);        \
        p4 = fmaf(v, bflo(h.z), p4);  p5 = fmaf(v, bfhi(h.z), p5);        \
        p6 = fmaf(v, bflo(h.w), p6);  p7 = fmaf(v, bfhi(h.w), p7); }

    for (int j = 0; j < 4; ++j) {
        const int ln = grp * 4 + j;                // local node 0..255
        if (ln >= nn) break;
        const int end = cur[ln];
        const int beg = end - nh[ln];

        float p0 = 0.f, p1 = 0.f, p2 = 0.f, p3 = 0.f;
        float p4 = 0.f, p5 = 0.f, p6 = 0.f, p7 = 0.f;

        int e = beg;
        for (; e + 7 < end; e += 8) {
            const int2 r0 = srec[e + 0], r1 = srec[e + 1];
            const int2 r2 = srec[e + 2], r3 = srec[e + 3];
            const int2 r4 = srec[e + 4], r5 = srec[e + 5];
            const int2 r6 = srec[e + 6], r7 = srec[e + 7];
            const uint4 h0 = *((const uint4*)(H + (size_t)r0.x * OUT_DIM) + c);
            const uint4 h1 = *((const uint4*)(H + (size_t)r1.x * OUT_DIM) + c);
            const uint4 h2 = *((const uint4*)(H + (size_t)r2.x * OUT_DIM) + c);
            const uint4 h3 = *((const uint4*)(H + (size_t)r3.x * OUT_DIM) + c);
            const uint4 h4 = *((const uint4*)(H + (size_t)r4.x * OUT_DIM) + c);
            const uint4 h5 = *((const uint4*)(H + (size_t)r5.x * OUT_DIM) + c);
            const uint4 h6 = *((const uint4*)(H + (size_t)r6.x * OUT_DIM) + c);
            const uint4 h7 = *((const uint4*)(H + (size_t)r7.x * OUT_DIM) + c);
            ACC(h0, __int_as_float(r0.y));  ACC(h1, __int_as_float(r1.y));
            ACC(h2, __int_as_float(r2.y));  ACC(h3, __int_as_float(r3.y));
            ACC(h4, __int_as_float(r4.y));  ACC(h5, __int_as_float(r5.y));
            ACC(h6, __int_as_float(r6.y));  ACC(h7, __int_as_float(r7.y));
        }
        for (; e + 1 < end; e += 2) {
            const int2 r0 = srec[e + 0], r1 = srec[e + 1];
            const uint4 h0 = *((const uint4*)(H + (size_t)r0.x * OUT_DIM) + c);
            const uint4 h1 = *((const uint4*)(H + (size_t)r1.x * OUT_DIM) + c);
            ACC(h0, __int_as_float(r0.y));  ACC(h1, __int_as_float(r1.y));
        }
        if (e < end) {
            const int2 r0 = srec[e];
            const uint4 h0 = *((const uint4*)(H + (size_t)r0.x * OUT_DIM) + c);
            ACC(h0, __int_as_float(r0.y));
        }

        float* op = out + (size_t)(node0 + ln) * OUT_DIM + c * 8;
        float4 o0, o1;
        o0.x = fmaxf(p0, 0.f); o0.y = fmaxf(p1, 0.f);
        o0.z = fmaxf(p2, 0.f); o0.w = fmaxf(p3, 0.f);
        o1.x = fmaxf(p4, 0.f); o1.y = fmaxf(p5, 0.f);
        o1.z = fmaxf(p6, 0.f); o1.w = fmaxf(p7, 0.f);
        *reinterpret_cast<float4*>(op)     = o0;
        *reinterpret_cast<float4*>(op + 4) = o1;
    }
#undef ACC
}

extern "C" void kernel_launch(void* const* d_in, const int* in_sizes, int n_in,
                              void* d_out, int out_size, void* d_ws, size_t ws_size,
                              hipStream_t stream) {
    const float* X    = (const float*)d_in[0];   // [N_NODES, IN_DIM]
    const float* W    = (const float*)d_in[1];   // [IN_DIM, OUT_DIM]
    const int*   esrc = (const int*)d_in[2];     // [N_EDGES]
    const int*   edst = (const int*)d_in[3];     // [N_EDGES]
    const float* eval = (const float*)d_in[4];   // [N_EDGES]
    float*       out  = (float*)d_out;           // [N_NODES, OUT_DIM]

    // Workspace layout (~42 MB)
    char* ws = (char*)d_ws;
    ushort* Hb     = (ushort*)ws;  ws += (size_t)N_NODES * OUT_DIM * sizeof(ushort);   // 25.6 MB
    ushort* Wp     = (ushort*)ws;  ws += (size_t)4096 * 8 * sizeof(ushort);            // 64 KB
    int*    bcur   = (int*)ws;     ws += (size_t)NBUCK * BSTRIDE * 4;                  // 12.5 KB padded
    int2*   binned = (int2*)ws;    // 16.1 MB

    // 1) Pack W (+ zero bucket cursors); interleaved [GEMM || sorted coarse]
    pack_w<<<16, 256, 0, stream>>>(W, Wp, bcur);
    gemm_coarse<<<TOTAL_BLOCKS, 256, 0, stream>>>(X, (const bf16x8*)Wp, Hb,
                                                  esrc, edst, eval, bcur, binned);

    // 2) Fused per-half-bucket CSR-in-LDS + pull-SpMM + ReLU
    bin_pull<<<2 * NBUCK, 1024, 0, stream>>>(bcur, binned, Hb, out);
}

// Round 26
// 108.469 us; speedup vs baseline: 1.1328x; 1.0438x over previous
//
#include <hip/hip_runtime.h>
#include <hip/hip_bf16.h>

#define N_NODES 100000
#define N_EDGES 1600000
#define IN_DIM  256
#define OUT_DIM 128

#define GEMM_ROWS   32
#define GEMM_BLOCKS (N_NODES / GEMM_ROWS)          // 3125 exact

#define NBUCK   196                                // ceil(100000 / 512)
#define BSHIFT  9                                  // 512 nodes per bucket
#define BCAP    10240                              // per-bucket capacity (mean 8192)
#define BSTRIDE 16                                 // bcur padding: 1 line per bucket
#define EPB     2048                               // edges per coarse block
#define BIN_BLOCKS ((N_EDGES + EPB - 1) / EPB)     // 782
#define TOTAL_BLOCKS (GEMM_BLOCKS + BIN_BLOCKS)    // 3907
#define RPT     10                                 // BCAP / 1024 recs per thread

typedef __attribute__((ext_vector_type(8))) short bf16x8;
typedef __attribute__((ext_vector_type(4))) float f32x4;

__device__ __forceinline__ ushort f2bf(float f) {
    union { float f; unsigned u; } v; v.f = f;
    unsigned r = v.u + 0x7FFF + ((v.u >> 16) & 1);   // RNE
    return (ushort)(r >> 16);
}
__device__ __forceinline__ float bflo(unsigned u) {
    union { unsigned u; float f; } v; v.u = u << 16; return v.f;
}
__device__ __forceinline__ float bfhi(unsigned u) {
    union { unsigned u; float f; } v; v.u = u & 0xFFFF0000u; return v.f;
}

// ------- Pack W[256,128] f32 -> bf16 fragment-major (+ zero bcur) ----------
__global__ __launch_bounds__(256) void pack_w(const float* __restrict__ W,
                                              ushort* __restrict__ Wp,
                                              int* __restrict__ bcur) {
    const int t = blockIdx.x * 256 + threadIdx.x;
    if (blockIdx.x == 0) {                         // fold: zero bucket cursors
        for (int i = threadIdx.x; i < NBUCK * BSTRIDE; i += 256) bcur[i] = 0;
    }
    if (t >= 4096) return;
    const int kk = t >> 9, n = (t >> 6) & 7, l = t & 63;
    const int kbase = kk * 32 + (l >> 4) * 8;
    const int col   = n * 16 + (l & 15);
    ushort* o = Wp + (size_t)t * 8;
#pragma unroll
    for (int j = 0; j < 8; ++j)
        o[j] = f2bf(W[(size_t)(kbase + j) * OUT_DIM + col]);
}

// --- Fused (4:1 INTERLEAVED): 32-row MFMA GEMM (B-frags preloaded to regs) -
// --- + EPB-2048 sorted coarse binning. launch_bounds(256,5): 102 VGPRs. ----
__global__ __launch_bounds__(256, 5) void gemm_coarse(const float* __restrict__ X,
                                                      const bf16x8* __restrict__ Bp,
                                                      ushort* __restrict__ H,
                                                      const int* __restrict__ esrc,
                                                      const int* __restrict__ edst,
                                                      const float* __restrict__ eval,
                                                      int* __restrict__ bcur,
                                                      int2* __restrict__ binned) {
    __shared__ char smem[22656];                   // GEMM 16.1KB / coarse 22.1KB

    const int tid  = threadIdx.x;
    const int lane = tid & 63;
    const int wv   = tid >> 6;
    const int bid  = blockIdx.x;

    const bool is_coarse = ((bid % 5) == 4) || (bid == TOTAL_BLOCKS - 1);

    if (is_coarse) {
        // ---- coarse binning with in-LDS counting sort (2048-edge chunk) ----
        const int blk = (bid == TOTAL_BLOCKS - 1) ? (BIN_BLOCKS - 1) : (bid / 5);
        int*   cnt   = (int*)smem;                 // [196]
        int*   lbase = (int*)smem + 256;           // [196]
        int*   sbase = (int*)smem + 512;           // [196]
        int*   cur   = (int*)smem + 768;           // [196]
        int2*  lrec  = (int2*)(smem + 4096);       // [2048] 16 KB
        unsigned char* lbid = (unsigned char*)smem + 20480;  // [2048]

        const int cb  = blk * EPB;
        const int lim = (N_EDGES - cb < EPB) ? (N_EDGES - cb) : EPB;

        if (tid < NBUCK) cnt[tid] = 0;
        __syncthreads();
        for (int i = tid; i < lim; i += 256)
            atomicAdd(&cnt[edst[cb + i] >> BSHIFT], 1);
        __syncthreads();

        // exclusive scan of cnt[0..195] -> lbase
        {
            __shared__ int wsum[4];
            const int v = (tid < NBUCK) ? cnt[tid] : 0;
            int sv = v;
#pragma unroll
            for (int d = 1; d < 64; d <<= 1) {
                const int t = __shfl_up(sv, d, 64);
                if (lane >= d) sv += t;
            }
            if (lane == 63) wsum[wv] = sv;
            __syncthreads();
            int wx = 0;
#pragma unroll
            for (int w = 0; w < 4; ++w) if (w < wv) wx += wsum[w];
            if (tid < NBUCK) {
                const int ex = wx + sv - v;
                lbase[tid] = ex;
                cur[tid]   = ex;
                sbase[tid] = v ? atomicAdd(&bcur[tid * BSTRIDE], v) : 0;
            }
        }
        __syncthreads();

        // scatter into LDS in bucket-sorted order
        for (int i = tid; i < lim; i += 256) {
            const int d = edst[cb + i];
            const int b = d >> BSHIFT;
            const int pos = atomicAdd(&cur[b], 1);
            int2 rec;
            rec.x = esrc[cb + i] | ((d & 511) << 20);
            rec.y = __float_as_int(eval[cb + i]);
            lrec[pos] = rec;
            lbid[pos] = (unsigned char)b;
        }
        __syncthreads();

        // write out sorted: consecutive i -> consecutive global positions
        for (int i = tid; i < lim; i += 256) {
            const int b   = lbid[i];
            const int off = sbase[b] + (i - lbase[b]);
            if (off < BCAP)
                binned[(size_t)b * BCAP + off] = lrec[i];
        }
        return;
    }

    // ---- GEMM: 32 rows x 128 cols; 4 waves each own 32 rows x 32 cols ----
    const int gidx = bid - bid / 5;                // de-interleaved GEMM index
    ushort* xt = (ushort*)smem;
    const int row0 = gidx * GEMM_ROWS;             // exact: no bounds checks
    const int wid  = wv;                           // col quarter 0..3

    // stage: 8 iters, 4 rows/iter, convert f32->bf16, swizzled LDS store
#pragma unroll 4
    for (int it = 0; it < 8; ++it) {
        const int tr = it * 4 + (tid >> 6);
        const int tc = (tid & 63) * 4;
        const float4 v = *reinterpret_cast<const float4*>(
            X + (size_t)(row0 + tr) * IN_DIM + tc);
        ushort4 b4;
        b4.x = f2bf(v.x); b4.y = f2bf(v.y); b4.z = f2bf(v.z); b4.w = f2bf(v.w);
        const int byte = (tr * 512 + tc * 2) ^ ((tr & 7) << 4);
        *reinterpret_cast<ushort4*>((char*)xt + byte) = b4;
    }

    // preload ALL B fragments for this wave (16 x 16B = 64 VGPRs, L2-hot);
    bf16x8 Bfr[8][2];
#pragma unroll
    for (int kk = 0; kk < 8; ++kk)
#pragma unroll
        for (int n = 0; n < 2; ++n)
            Bfr[kk][n] = Bp[(size_t)(kk * 8 + wid * 2 + n) * 64 + lane];

    __syncthreads();

    const int rlo  = lane & 15;
    const int kseg = lane >> 4;
    const int rl0  = rlo;                          // A-frag local rows
    const int rl1  = rlo + 16;
    const int rxor = (rlo & 7) << 4;

    f32x4 acc[2][2] = {};

#pragma unroll
    for (int kk = 0; kk < 8; ++kk) {
        const int cb2 = (kk * 64 + kseg * 16) ^ rxor;
        const bf16x8 A0 = *reinterpret_cast<const bf16x8*>((const char*)xt + rl0 * 512 + cb2);
        const bf16x8 A1 = *reinterpret_cast<const bf16x8*>((const char*)xt + rl1 * 512 + cb2);
#pragma unroll
        for (int n = 0; n < 2; ++n) {
            acc[0][n] = __builtin_amdgcn_mfma_f32_16x16x32_bf16(A0, Bfr[kk][n], acc[0][n], 0, 0, 0);
            acc[1][n] = __builtin_amdgcn_mfma_f32_16x16x32_bf16(A1, Bfr[kk][n], acc[1][n], 0, 0, 0);
        }
    }

    // C/D layout: col = wid*32 + n*16 + rlo, row = i*16 + kseg*4 + r
#pragma unroll
    for (int i = 0; i < 2; ++i)
#pragma unroll
        for (int r = 0; r < 4; ++r)
#pragma unroll
            for (int n = 0; n < 2; ++n)
                H[(size_t)(row0 + i * 16 + kseg * 4 + r) * OUT_DIM
                  + wid * 32 + n * 16 + rlo] = f2bf(acc[i][n][r]);
}

// --- Fused fine+pull, records sorted into LDS (no global recs array) -------
// Block b: load bucket b's records into REGISTERS (one global pass) -> hist
// -> local scan -> scatter regs -> LDS sorted records -> pull from LDS.
__global__ __launch_bounds__(1024) void bin_pull(const int* __restrict__ bcur,
                                                 const int2* __restrict__ binned,
                                                 const ushort* __restrict__ H,
                                                 float* __restrict__ out) {
    __shared__ int2 srec[BCAP];                    // 80 KB sorted records
    __shared__ int nh[512];
    __shared__ int cur[512];
    __shared__ int ws[4];
    const int b   = blockIdx.x;
    const int tid = threadIdx.x, lane = tid & 63, wid = tid >> 6;
    const int node0 = b << BSHIFT;
    int nn = N_NODES - node0; if (nn > 512) nn = 512;
    int size = bcur[b * BSTRIDE]; if (size > BCAP) size = BCAP;
    const int2* in = binned + (size_t)b * BCAP;

    if (tid < 512) nh[tid] = 0;
    __syncthreads();

    // single global pass: load records to registers + histogram
    int2 rg[RPT];
#pragma unroll
    for (int it = 0; it < RPT; ++it) {
        const int k = tid + it * 1024;
        if (k < size) {
            rg[it] = in[k];
            atomicAdd(&nh[(rg[it].x >> 20) & 511], 1);
        }
    }
    __syncthreads();

    // exclusive scan over nh[0..511] (bucket-local); threads 0..255 own pairs
    int a0 = 0, ts = 0, sv = 0;
    if (tid < 256) {
        a0 = nh[2 * tid];
        const int a1 = nh[2 * tid + 1];
        ts = a0 + a1;
        sv = ts;
#pragma unroll
        for (int d = 1; d < 64; d <<= 1) {
            const int t = __shfl_up(sv, d, 64);
            if (lane >= d) sv += t;
        }
        if (lane == 63) ws[wid] = sv;
    }
    __syncthreads();
    if (tid < 256) {
        int wx = 0;
#pragma unroll
        for (int w = 0; w < 4; ++w) if (w < wid) wx += ws[w];
        const int ex = wx + sv - ts;               // exclusive prefix of pair
        cur[2 * tid]     = ex;
        cur[2 * tid + 1] = ex + a0;
    }
    __syncthreads();

    // scatter from registers -> LDS sorted by node
#pragma unroll
    for (int it = 0; it < RPT; ++it) {
        const int k = tid + it * 1024;
        if (k < size) {
            const int2 r = rg[it];
            const int pos = atomicAdd(&cur[(r.x >> 20) & 511], 1);
            int2 o; o.x = r.x & 0xFFFFF; o.y = r.y;
            srec[pos] = o;
        }
    }
    __syncthreads();                               // bucket fully sorted in LDS

    // ---- pull: 64 groups x 16 lanes; group handles 8 consecutive nodes ----
    const int grp = tid >> 4;                      // 0..63
    const int c   = tid & 15;                      // 16B col-chunk

#define ACC(h, v)  {                                                      \
        p0 = fmaf(v, bflo(h.x), p0);  p1 = fmaf(v, bfhi(h.x), p1);        \
        p2 = fmaf(v, bflo(h.y), p2);  p3 = fmaf(v, bfhi(h.y), p3);        \
        p4 = fmaf(v, bflo(h.z), p4);  p5 = fmaf(v, bfhi(h.z), p5);        \
        p6 = fmaf(v, bflo(h.w), p6);  p7 = fmaf(v, bfhi(h.w), p7); }

    for (int j = 0; j < 8; ++j) {
        const int ln = grp * 8 + j;                // local node 0..511
        if (ln >= nn) break;
        const int end = cur[ln];
        const int beg = end - nh[ln];

        float p0 = 0.f, p1 = 0.f, p2 = 0.f, p3 = 0.f;
        float p4 = 0.f, p5 = 0.f, p6 = 0.f, p7 = 0.f;

        int e = beg;
        for (; e + 7 < end; e += 8) {
            const int2 r0 = srec[e + 0], r1 = srec[e + 1];
            const int2 r2 = srec[e + 2], r3 = srec[e + 3];
            const int2 r4 = srec[e + 4], r5 = srec[e + 5];
            const int2 r6 = srec[e + 6], r7 = srec[e + 7];
            const uint4 h0 = *((const uint4*)(H + (size_t)r0.x * OUT_DIM) + c);
            const uint4 h1 = *((const uint4*)(H + (size_t)r1.x * OUT_DIM) + c);
            const uint4 h2 = *((const uint4*)(H + (size_t)r2.x * OUT_DIM) + c);
            const uint4 h3 = *((const uint4*)(H + (size_t)r3.x * OUT_DIM) + c);
            const uint4 h4 = *((const uint4*)(H + (size_t)r4.x * OUT_DIM) + c);
            const uint4 h5 = *((const uint4*)(H + (size_t)r5.x * OUT_DIM) + c);
            const uint4 h6 = *((const uint4*)(H + (size_t)r6.x * OUT_DIM) + c);
            const uint4 h7 = *((const uint4*)(H + (size_t)r7.x * OUT_DIM) + c);
            ACC(h0, __int_as_float(r0.y));  ACC(h1, __int_as_float(r1.y));
            ACC(h2, __int_as_float(r2.y));  ACC(h3, __int_as_float(r3.y));
            ACC(h4, __int_as_float(r4.y));  ACC(h5, __int_as_float(r5.y));
            ACC(h6, __int_as_float(r6.y));  ACC(h7, __int_as_float(r7.y));
        }
        for (; e + 1 < end; e += 2) {
            const int2 r0 = srec[e + 0], r1 = srec[e + 1];
            const uint4 h0 = *((const uint4*)(H + (size_t)r0.x * OUT_DIM) + c);
            const uint4 h1 = *((const uint4*)(H + (size_t)r1.x * OUT_DIM) + c);
            ACC(h0, __int_as_float(r0.y));  ACC(h1, __int_as_float(r1.y));
        }
        if (e < end) {
            const int2 r0 = srec[e];
            const uint4 h0 = *((const uint4*)(H + (size_t)r0.x * OUT_DIM) + c);
            ACC(h0, __int_as_float(r0.y));
        }

        float* op = out + (size_t)(node0 + ln) * OUT_DIM + c * 8;
        float4 o0, o1;
        o0.x = fmaxf(p0, 0.f); o0.y = fmaxf(p1, 0.f);
        o0.z = fmaxf(p2, 0.f); o0.w = fmaxf(p3, 0.f);
        o1.x = fmaxf(p4, 0.f); o1.y = fmaxf(p5, 0.f);
        o1.z = fmaxf(p6, 0.f); o1.w = fmaxf(p7, 0.f);
        *reinterpret_cast<float4*>(op)     = o0;
        *reinterpret_cast<float4*>(op + 4) = o1;
    }
#undef ACC
}

extern "C" void kernel_launch(void* const* d_in, const int* in_sizes, int n_in,
                              void* d_out, int out_size, void* d_ws, size_t ws_size,
                              hipStream_t stream) {
    const float* X    = (const float*)d_in[0];   // [N_NODES, IN_DIM]
    const float* W    = (const float*)d_in[1];   // [IN_DIM, OUT_DIM]
    const int*   esrc = (const int*)d_in[2];     // [N_EDGES]
    const int*   edst = (const int*)d_in[3];     // [N_EDGES]
    const float* eval = (const float*)d_in[4];   // [N_EDGES]
    float*       out  = (float*)d_out;           // [N_NODES, OUT_DIM]

    // Workspace layout (~42 MB)
    char* ws = (char*)d_ws;
    ushort* Hb     = (ushort*)ws;  ws += (size_t)N_NODES * OUT_DIM * sizeof(ushort);   // 25.6 MB
    ushort* Wp     = (ushort*)ws;  ws += (size_t)4096 * 8 * sizeof(ushort);            // 64 KB
    int*    bcur   = (int*)ws;     ws += (size_t)NBUCK * BSTRIDE * 4;                  // 12.5 KB padded
    int2*   binned = (int2*)ws;    // 16.1 MB

    // 1) Pack W (+ zero bucket cursors); interleaved [GEMM || sorted coarse]
    pack_w<<<16, 256, 0, stream>>>(W, Wp, bcur);
    gemm_coarse<<<TOTAL_BLOCKS, 256, 0, stream>>>(X, (const bf16x8*)Wp, Hb,
                                                  esrc, edst, eval, bcur, binned);

    // 2) Fused per-bucket CSR-in-LDS + pull-SpMM + ReLU
    bin_pull<<<NBUCK, 1024, 0, stream>>>(bcur, binned, Hb, out);
}